// Round 5
// baseline (72740.741 us; speedup 1.0000x reference)
//
#include <hip/hip_runtime.h>
#include <hip/hip_bf16.h>

// LSTM classifier: emb gather -> input GEMM (fp16 MFMA) -> persistent
// recurrence kernel (64 WGs x 256 thr; 4 independent batch-streams
// interleaved per wave to hide LLC sync latency; W_hh in LDS; sc1/LLC
// transport; packed per-wave u16 flags, no barriers/RMW/fences) -> logits.
//
// Workspace layout (bytes):
//   emb16   @ 0          : 50257*1024*2 = 102,926,336
//   wih16   @ 102926336  : 4096*1024*2  =   8,388,608
//   wr16    @ 111314944  : 4096*1024*2  =   8,388,608   (W_hh reordered, fp16)
//   bias    @ 119703552  : 4096*4       =      16,384   (b_ih + b_hh, f32)
//   xg      @ 119719936  : 65536*4096*2 = 536,870,912   (x_gates fp16, [t][b][R'])
//   h_all   @ 656590848  : 2049*32*1024*2 = 134,283,264 (h per step, fp16)
//   flags   @ 790874112  : 4*64*128     =      32,768   (u64 per (stream,WG): 4 u16 wave flags)
//   total: 790,906,880

typedef _Float16 f16;
typedef _Float16 f16x8 __attribute__((ext_vector_type(8)));
typedef _Float16 f16x4 __attribute__((ext_vector_type(4)));
typedef float    f32x4 __attribute__((ext_vector_type(4)));
typedef unsigned long long u64;

#define B_    32
#define T_    2048
#define W_    1024
#define H_    1024
#define G4_   4096

__device__ __forceinline__ void gl_lds16(const void* g, void* l) {
  __builtin_amdgcn_global_load_lds(
      (const __attribute__((address_space(1))) void*)g,
      (__attribute__((address_space(3))) void*)l, 16, 0, 0);
}

// agent-scope (sc1 / LLC-coherent) helpers — bypass non-coherent XCD L2s
__device__ __forceinline__ u64 llc_ld64(const void* p) {
  return __hip_atomic_load((const u64*)p, __ATOMIC_RELAXED, __HIP_MEMORY_SCOPE_AGENT);
}
__device__ __forceinline__ void llc_st16(void* p, unsigned short v) {
  __hip_atomic_store((unsigned short*)p, v, __ATOMIC_RELAXED, __HIP_MEMORY_SCOPE_AGENT);
}

// fast activations: v_exp_f32 + v_rcp_f32 (no libm branches on critical path)
__device__ __forceinline__ float fast_sigmoid(float v) {
  return __builtin_amdgcn_rcpf(1.f + __expf(-v));
}
__device__ __forceinline__ float fast_tanh(float v) {
  return 1.f - 2.f * __builtin_amdgcn_rcpf(1.f + __expf(2.f * v));
}

// ---------------- conversions ----------------

__global__ void k_cvt_f16(const float* __restrict__ in, f16* __restrict__ out, long n4) {
  long i = (long)blockIdx.x * blockDim.x + threadIdx.x;
  if (i >= n4) return;
  float4 v = ((const float4*)in)[i];
  f16x4 o; o[0] = (f16)v.x; o[1] = (f16)v.y; o[2] = (f16)v.z; o[3] = (f16)v.w;
  *(f16x4*)(out + i * 4) = o;
}

// W_hh row (q*1024 + j) -> wr16 row R' = (j>>4)*64 + (j&15)*4 + q; fp16.
// => WG wid owns contiguous rows [wid*64, wid*64+64) = h-dims [wid*16, +16).
__global__ void k_whh_reorder(const float* __restrict__ whh, f16* __restrict__ wr) {
  unsigned i = blockIdx.x * blockDim.x + threadIdx.x;   // one thread per 8 elems
  unsigned e0 = i * 8;
  unsigned R = e0 >> 10, k = e0 & 1023;
  unsigned q = R >> 10, j = R & 1023;
  unsigned outR = ((j >> 4) << 6) + ((j & 15) << 2) + q;
  float4 v0 = ((const float4*)whh)[e0 / 4];
  float4 v1 = ((const float4*)whh)[e0 / 4 + 1];
  f16x8 o;
  o[0] = (f16)v0.x; o[1] = (f16)v0.y; o[2] = (f16)v0.z; o[3] = (f16)v0.w;
  o[4] = (f16)v1.x; o[5] = (f16)v1.y; o[6] = (f16)v1.z; o[7] = (f16)v1.w;
  *(f16x8*)&wr[((size_t)outR << 10) + k] = o;
}

__global__ void k_bias(const float* __restrict__ bi, const float* __restrict__ bh,
                       float* __restrict__ bo) {
  unsigned i = blockIdx.x * blockDim.x + threadIdx.x;
  if (i < G4_) bo[i] = bi[i] + bh[i];
}

// ---------------- input GEMM: xg[m][R'(n)] = emb[seq] @ W_ih^T + bias ----------------
// m = t*32 + b (so xg layout is [t][b][R']); 128x128 tile, BK=64, 4 waves.

__global__ __launch_bounds__(256) void k_gemm_xg(
    const int* __restrict__ seq, const f16* __restrict__ emb16,
    const f16* __restrict__ wih16, const float* __restrict__ bias,
    f16* __restrict__ xg) {
  __shared__ f16 As[128 * 64];
  __shared__ f16 Bs[128 * 64];
  const unsigned tid = threadIdx.x;
  const unsigned w = tid >> 6, lane = tid & 63;
  const unsigned bid = blockIdx.x;
  const unsigned tn = bid & 31, tm = bid >> 5;
  const unsigned wm = (w >> 1) * 64, wn = (w & 1) * 64;

  f32x4 zero = {0.f, 0.f, 0.f, 0.f};
  f32x4 acc[4][4];
#pragma unroll
  for (int i = 0; i < 4; ++i)
#pragma unroll
    for (int j = 0; j < 4; ++j) acc[i][j] = zero;

  for (unsigned kk = 0; kk < 16; ++kk) {
    const unsigned k0 = kk * 64;
#pragma unroll
    for (unsigned c = 0; c < 4; ++c) {
      unsigned idx = c * 256 + tid;
      unsigned row = idx >> 3, ch = idx & 7;
      unsigned chs = ch ^ (row & 7);
      unsigned m = tm * 128 + row;
      unsigned t = m >> 5, b = m & 31;
      int e = seq[b * 2048 + t];
      const f16* src = emb16 + ((size_t)e << 10) + k0 + chs * 8;
      gl_lds16(src, (char*)As + c * 4096 + w * 1024);
    }
#pragma unroll
    for (unsigned c = 0; c < 4; ++c) {
      unsigned idx = c * 256 + tid;
      unsigned row = idx >> 3, ch = idx & 7;
      unsigned chs = ch ^ (row & 7);
      unsigned n = tn * 128 + row;
      const f16* src = wih16 + ((size_t)n << 10) + k0 + chs * 8;
      gl_lds16(src, (char*)Bs + c * 4096 + w * 1024);
    }
    __syncthreads();
#pragma unroll
    for (unsigned ks = 0; ks < 2; ++ks) {
      f16x8 af[4], bf[4];
      unsigned kc = ks * 4 + (lane >> 4);
#pragma unroll
      for (unsigned fm = 0; fm < 4; ++fm) {
        unsigned r = wm + fm * 16 + (lane & 15);
        af[fm] = *(const f16x8*)&As[r * 64 + ((kc ^ (r & 7)) << 3)];
      }
#pragma unroll
      for (unsigned fn = 0; fn < 4; ++fn) {
        unsigned r = wn + fn * 16 + (lane & 15);
        bf[fn] = *(const f16x8*)&Bs[r * 64 + ((kc ^ (r & 7)) << 3)];
      }
#pragma unroll
      for (unsigned fm = 0; fm < 4; ++fm)
#pragma unroll
        for (unsigned fn = 0; fn < 4; ++fn)
          acc[fm][fn] = __builtin_amdgcn_mfma_f32_16x16x32_f16(af[fm], bf[fn], acc[fm][fn], 0, 0, 0);
    }
    __syncthreads();
  }
  // epilogue: + bias, fp16 store into gate-interleaved layout R'
#pragma unroll
  for (unsigned fn = 0; fn < 4; ++fn) {
    unsigned n = tn * 128 + wn + fn * 16 + (lane & 15);
    unsigned q = n >> 10, j = n & 1023;
    unsigned Rp = ((j >> 4) << 6) + ((j & 15) << 2) + q;
    float bv = bias[n];
#pragma unroll
    for (unsigned fm = 0; fm < 4; ++fm) {
#pragma unroll
      for (unsigned rg = 0; rg < 4; ++rg) {
        unsigned m = tm * 128 + wm + fm * 16 + (lane >> 4) * 4 + rg;
        xg[(size_t)m * G4_ + Rp] = (f16)(acc[fm][fn][rg] + bv);
      }
    }
  }
}

// ---------------- persistent LSTM recurrence ----------------
// 64 WGs x 256 threads (4 waves; wave w = n-tile, rows [w*16, w*16+16) of the
// WG's 64-row W slice, staged once in 128KB LDS).
// Batch dim is independent -> 4 streams of 8 batches, interleaved per wave:
//   per t: for s in 0..3: { poll s-flags >= t-1; compute stream s step t }
// so each stream's sync latency hides under the other 3 streams' compute.
// A-frags: M=8 (rows 8..15 zero). h transport via relaxed sc1 (LLC) loads /
// 16-bit stores. Flags: u64 per (s,wid) = 4 packed u16 (one per wave), each
// wave's lane0 stores its own u16 after draining h-stores (vmcnt(4): the 4
// younger xg prefetch loads may stay in flight; m135 oldest-first semantics).
// ZERO barriers, ZERO RMW atomics, ZERO fences in the step loop.

__global__ __launch_bounds__(256) void k_lstm(
    const f16* __restrict__ xg, const f16* __restrict__ wr16,
    f16* __restrict__ h_all, u64* __restrict__ flags) {
  __shared__ f16 Wl[64 * 1024];     // 128 KB
  const unsigned tid = threadIdx.x;
  const unsigned w = tid >> 6, lane = tid & 63;
  const unsigned wid = blockIdx.x;          // 0..63

  // stage W_hh slice (64 rows x 1024 f16), source-swizzled, linear LDS dest
  for (unsigned c = 0; c < 32; ++c) {
    unsigned idx = c * 256 + tid;
    unsigned row = idx >> 7, ch = idx & 127;
    unsigned chs = ch ^ (row & 7);
    const f16* src = wr16 + (((size_t)wid * 64 + row) << 10) + chs * 8;
    gl_lds16(src, (char*)Wl + c * 4096 + w * 1024);
  }
  __syncthreads();    // one-time: W visible to all 4 waves

  const unsigned rl = lane & 15, hi = lane >> 4;
  const unsigned q = rl & 3;                 // gate id within quad
  const unsigned rWl = w * 16 + rl;          // local W row 0..63
  const unsigned d = wid * 16 + w * 4 + (rl >> 2);   // global h-dim
  const bool wr_h = (q == 0) && (hi < 2);    // stores valid batch rows only
  const bool ld_x = (hi < 2);

  float c_st[4][4];
#pragma unroll
  for (int s = 0; s < 4; ++s)
#pragma unroll
    for (int z = 0; z < 4; ++z) c_st[s][z] = 0.f;

  // x_gates prefetch for t=1, all streams
  float xv[4][4];
#pragma unroll
  for (int s = 0; s < 4; ++s) {
    const f16* xp = xg + ((size_t)(s * 8 + hi * 4)) * G4_ + wid * 64 + rWl;
#pragma unroll
    for (int z = 0; z < 4; ++z) xv[s][z] = ld_x ? (float)xp[(size_t)z * G4_] : 0.f;
  }

  for (unsigned t = 1; t <= (unsigned)T_; ++t) {
#pragma unroll
    for (int s = 0; s < 4; ++s) {
      // ---- wait for all 256 wave-flags of stream s to reach t-1 ----
      if (t > 1) {
        const unsigned tgt = t - 1;
        const char* fp = (const char*)flags + (((unsigned)s * 64 + lane) << 7);
        while (true) {
          u64 v = llc_ld64(fp);
          bool ok = (unsigned)(v & 0xffffu) >= tgt &&
                    (unsigned)((v >> 16) & 0xffffu) >= tgt &&
                    (unsigned)((v >> 32) & 0xffffu) >= tgt &&
                    (unsigned)(v >> 48) >= tgt;
          if (__all((int)ok)) break;
          __builtin_amdgcn_s_sleep(1);
        }
      }
      // ---- gates_partial = h_s[t-1] (M=8) @ Whh_slice[n-tile]^T ----
      f32x4 acc0 = {0.f, 0.f, 0.f, 0.f};
      f32x4 acc1 = {0.f, 0.f, 0.f, 0.f};
      const f16* hrow = h_all + ((size_t)(t - 1) * B_ + s * 8 + rl) * H_ + hi * 8;
#pragma unroll
      for (unsigned ks = 0; ks < 32; ks += 2) {
        union { u64 u[2]; f16x8 v; } ua, ub;
        if (rl < 8) {
          ua.u[0] = llc_ld64(hrow + ks * 32);
          ua.u[1] = llc_ld64(hrow + ks * 32 + 4);
          ub.u[0] = llc_ld64(hrow + ks * 32 + 32);
          ub.u[1] = llc_ld64(hrow + ks * 32 + 36);
        } else {
          ua.u[0] = 0; ua.u[1] = 0; ub.u[0] = 0; ub.u[1] = 0;
        }
        unsigned ck0 = ks * 4 + hi, ck1 = ck0 + 4;
        f16x8 b0 = *(const f16x8*)&Wl[rWl * 1024 + ((ck0 ^ (rWl & 7)) << 3)];
        f16x8 b1 = *(const f16x8*)&Wl[rWl * 1024 + ((ck1 ^ (rWl & 7)) << 3)];
        acc0 = __builtin_amdgcn_mfma_f32_16x16x32_f16(ua.v, b0, acc0, 0, 0, 0);
        acc1 = __builtin_amdgcn_mfma_f32_16x16x32_f16(ub.v, b1, acc1, 0, 0, 0);
      }
      // ---- activations + state update (quad holds i,f,g,o of one (d,b)) ----
      f16* hw = h_all + ((size_t)t * B_ + s * 8 + hi * 4) * H_ + d;
#pragma unroll
      for (int z = 0; z < 4; ++z) {
        float v = acc0[z] + acc1[z] + xv[s][z];
        float a = (q == 2) ? fast_tanh(v) : fast_sigmoid(v);
        float A1 = __shfl_xor(a, 1, 64);
        float A2 = __shfl_xor(a, 2, 64);
        float A3 = __shfl_xor(a, 3, 64);
        float iact = (q == 0) ? a  : (q == 1) ? A1 : (q == 2) ? A2 : A3;
        float fact = (q == 0) ? A1 : (q == 1) ? a  : (q == 2) ? A3 : A2;
        float gact = (q == 0) ? A2 : (q == 1) ? A3 : (q == 2) ? a  : A1;
        float oact = (q == 0) ? A3 : (q == 1) ? A2 : (q == 2) ? A1 : a;
        float cn = fact * c_st[s][z] + iact * gact;
        c_st[s][z] = cn;
        float hv = oact * fast_tanh(cn);
        if (wr_h) {
          f16 hv16 = (f16)hv;
          llc_st16(hw + (size_t)z * H_, __builtin_bit_cast(unsigned short, hv16));
        }
      }
      // compile-time fence: h-stores above must issue before xg loads below,
      // so vmcnt(4) (oldest-first) is guaranteed to cover all 4 h-stores.
      asm volatile("" ::: "memory");
      // ---- xg prefetch for (s, t+1): 4 VMEM loads, left in flight ----
      {
        unsigned tn_ = (t < (unsigned)T_) ? t : (unsigned)(T_ - 1);
        const f16* xp = xg + ((size_t)tn_ * B_ + s * 8 + hi * 4) * G4_ + wid * 64 + rWl;
#pragma unroll
        for (int z = 0; z < 4; ++z) xv[s][z] = ld_x ? (float)xp[(size_t)z * G4_] : 0.f;
      }
      // ---- release: drain h-stores (not the 4 xg loads), set wave flag ----
      asm volatile("s_waitcnt vmcnt(4)" ::: "memory");
      if (lane == 0) {
        llc_st16((char*)flags + (((unsigned)s * 64 + wid) << 7) + w * 2,
                 (unsigned short)t);
      }
    }
  }
}

// ---------------- logits: out[b][t][c] = relu(h[t+1]) . W_score[c] ----------------

__global__ __launch_bounds__(256) void k_logits(
    const f16* __restrict__ h_all, const float* __restrict__ wsc,
    float* __restrict__ out) {
  __shared__ float Ws[2048];
  unsigned tid = threadIdx.x;
  for (unsigned i = tid; i < 512; i += 256) ((float4*)Ws)[i] = ((const float4*)wsc)[i];
  __syncthreads();
  unsigned w = tid >> 6, lane = tid & 63;
  unsigned base = blockIdx.x * 64 + w * 16;
  for (unsigned i = 0; i < 16; ++i) {
    unsigned idx = base + i;                // 0..65535
    unsigned tt = idx >> 5, b = idx & 31;
    const f16* hp = h_all + ((size_t)(idx + 32)) * H_ + lane * 16;
    f16x8 ha = *(const f16x8*)hp;
    f16x8 hb = *(const f16x8*)(hp + 8);
    float s0 = 0.f, s1 = 0.f;
#pragma unroll
    for (int z = 0; z < 8; ++z) {
      float hv = fmaxf((float)ha[z], 0.f);
      s0 += hv * Ws[lane * 16 + z];
      s1 += hv * Ws[1024 + lane * 16 + z];
    }
#pragma unroll
    for (int z = 0; z < 8; ++z) {
      float hv = fmaxf((float)hb[z], 0.f);
      s0 += hv * Ws[lane * 16 + 8 + z];
      s1 += hv * Ws[1024 + lane * 16 + 8 + z];
    }
#pragma unroll
    for (int off = 32; off; off >>= 1) {
      s0 += __shfl_xor(s0, off, 64);
      s1 += __shfl_xor(s1, off, 64);
    }
    if (lane == 0) {
      out[((size_t)b * T_ + tt) * 2 + 0] = s0;
      out[((size_t)b * T_ + tt) * 2 + 1] = s1;
    }
  }
}

// ---------------- launch ----------------

extern "C" void kernel_launch(void* const* d_in, const int* in_sizes, int n_in,
                              void* d_out, int out_size, void* d_ws, size_t ws_size,
                              hipStream_t stream) {
  const int*   seq = (const int*)d_in[0];
  const float* emb = (const float*)d_in[1];
  const float* wih = (const float*)d_in[2];
  const float* whh = (const float*)d_in[3];
  const float* bih = (const float*)d_in[4];
  const float* bhh = (const float*)d_in[5];
  const float* wsc = (const float*)d_in[6];
  float* out = (float*)d_out;
  char* ws = (char*)d_ws;

  const size_t NEED = 790906880ull;
  if (ws_size < NEED) return;  // workspace too small: output stays zero (detectable)

  f16*  emb16 = (f16*)(ws);
  f16*  wih16 = (f16*)(ws + 102926336ull);
  f16*  wr16  = (f16*)(ws + 111314944ull);
  float* bias = (float*)(ws + 119703552ull);
  f16*  xg    = (f16*)(ws + 119719936ull);
  f16*  h_all = (f16*)(ws + 656590848ull);
  u64*  flags = (u64*)(ws + 790874112ull);

  hipMemsetAsync(h_all, 0, (size_t)B_ * H_ * 2, stream);      // h_0 = 0
  hipMemsetAsync(flags, 0, 4 * 64 * 128, stream);             // wave flags

  k_cvt_f16<<<50257, 256, 0, stream>>>(emb, emb16, 12865792L);
  k_cvt_f16<<<4096, 256, 0, stream>>>(wih, wih16, 1048576L);
  k_whh_reorder<<<2048, 256, 0, stream>>>(whh, wr16);
  k_bias<<<16, 256, 0, stream>>>(bih, bhh, bias);

  k_gemm_xg<<<16384, 256, 0, stream>>>(seq, emb16, wih16, bias, xg);
  k_lstm<<<64, 256, 0, stream>>>(xg, wr16, h_all, flags);
  k_logits<<<1024, 256, 0, stream>>>(h_all, wsc, out);
}

// Round 7
// 33865.973 us; speedup vs baseline: 2.1479x; 2.1479x over previous
//
#include <hip/hip_runtime.h>
#include <hip/hip_bf16.h>

// LSTM classifier: emb gather -> input GEMM (fp16 MFMA) -> persistent
// recurrence kernel (64 WGs x 512 thr; R2 topology + clean sc1 protocol:
// store-only flags, relaxed polls, ZERO cache-maintenance instructions
// in the step loop; W_hh in 128KB LDS) -> logits.
//
// Workspace layout (bytes):
//   emb16   @ 0          : 50257*1024*2 = 102,926,336
//   wih16   @ 102926336  : 4096*1024*2  =   8,388,608
//   wr16    @ 111314944  : 4096*1024*2  =   8,388,608   (W_hh reordered, fp16)
//   bias    @ 119703552  : 4096*4       =      16,384   (b_ih + b_hh, f32)
//   xg      @ 119719936  : 65536*4096*2 = 536,870,912   (x_gates fp16, [t][b][R'])
//   h_all   @ 656590848  : 2049*32*1024*2 = 134,283,264 (h per step, fp16)
//   flags   @ 790874112  : 64*32*4      =       8,192   (per-WG step flags)
//   total: 790,882,304

typedef _Float16 f16;
typedef _Float16 f16x8 __attribute__((ext_vector_type(8)));
typedef _Float16 f16x4 __attribute__((ext_vector_type(4)));
typedef float    f32x4 __attribute__((ext_vector_type(4)));
typedef unsigned long long u64;

#define B_    32
#define T_    2048
#define H_    1024
#define G4_   4096

__device__ __forceinline__ void gl_lds16(const void* g, void* l) {
  __builtin_amdgcn_global_load_lds(
      (const __attribute__((address_space(1))) void*)g,
      (__attribute__((address_space(3))) void*)l, 16, 0, 0);
}

// agent-scope (sc1 / LLC-coherent) helpers — bypass non-coherent XCD L2s,
// relaxed => no buffer_inv / buffer_wbl2 cache maintenance is emitted.
__device__ __forceinline__ u64 llc_ld64(const void* p) {
  return __hip_atomic_load((const u64*)p, __ATOMIC_RELAXED, __HIP_MEMORY_SCOPE_AGENT);
}
__device__ __forceinline__ void llc_st16(void* p, unsigned short v) {
  __hip_atomic_store((unsigned short*)p, v, __ATOMIC_RELAXED, __HIP_MEMORY_SCOPE_AGENT);
}

// fast activations: v_exp_f32 + v_rcp_f32 (no libm branches on critical path)
__device__ __forceinline__ float fast_sigmoid(float v) {
  return __builtin_amdgcn_rcpf(1.f + __expf(-v));
}
__device__ __forceinline__ float fast_tanh(float v) {
  return 1.f - 2.f * __builtin_amdgcn_rcpf(1.f + __expf(2.f * v));
}

// ---------------- conversions ----------------

__global__ void k_cvt_f16(const float* __restrict__ in, f16* __restrict__ out, long n4) {
  long i = (long)blockIdx.x * blockDim.x + threadIdx.x;
  if (i >= n4) return;
  float4 v = ((const float4*)in)[i];
  f16x4 o; o[0] = (f16)v.x; o[1] = (f16)v.y; o[2] = (f16)v.z; o[3] = (f16)v.w;
  *(f16x4*)(out + i * 4) = o;
}

// W_hh row (q*1024 + j) -> wr16 row R' = (j>>4)*64 + (j&15)*4 + q; fp16.
// => WG wid owns contiguous rows [wid*64, wid*64+64) = h-dims [wid*16, +16).
__global__ void k_whh_reorder(const float* __restrict__ whh, f16* __restrict__ wr) {
  unsigned i = blockIdx.x * blockDim.x + threadIdx.x;   // one thread per 8 elems
  unsigned e0 = i * 8;
  unsigned R = e0 >> 10, k = e0 & 1023;
  unsigned q = R >> 10, j = R & 1023;
  unsigned outR = ((j >> 4) << 6) + ((j & 15) << 2) + q;
  float4 v0 = ((const float4*)whh)[e0 / 4];
  float4 v1 = ((const float4*)whh)[e0 / 4 + 1];
  f16x8 o;
  o[0] = (f16)v0.x; o[1] = (f16)v0.y; o[2] = (f16)v0.z; o[3] = (f16)v0.w;
  o[4] = (f16)v1.x; o[5] = (f16)v1.y; o[6] = (f16)v1.z; o[7] = (f16)v1.w;
  *(f16x8*)&wr[((size_t)outR << 10) + k] = o;
}

__global__ void k_bias(const float* __restrict__ bi, const float* __restrict__ bh,
                       float* __restrict__ bo) {
  unsigned i = blockIdx.x * blockDim.x + threadIdx.x;
  if (i < G4_) bo[i] = bi[i] + bh[i];
}

// ---------------- input GEMM: xg[m][R'(n)] = emb[seq] @ W_ih^T + bias ----------------
// m = t*32 + b (so xg layout is [t][b][R']); 128x128 tile, BK=64, 4 waves.

__global__ __launch_bounds__(256) void k_gemm_xg(
    const int* __restrict__ seq, const f16* __restrict__ emb16,
    const f16* __restrict__ wih16, const float* __restrict__ bias,
    f16* __restrict__ xg) {
  __shared__ f16 As[128 * 64];
  __shared__ f16 Bs[128 * 64];
  const unsigned tid = threadIdx.x;
  const unsigned w = tid >> 6, lane = tid & 63;
  const unsigned bid = blockIdx.x;
  const unsigned tn = bid & 31, tm = bid >> 5;
  const unsigned wm = (w >> 1) * 64, wn = (w & 1) * 64;

  f32x4 zero = {0.f, 0.f, 0.f, 0.f};
  f32x4 acc[4][4];
#pragma unroll
  for (int i = 0; i < 4; ++i)
#pragma unroll
    for (int j = 0; j < 4; ++j) acc[i][j] = zero;

  for (unsigned kk = 0; kk < 16; ++kk) {
    const unsigned k0 = kk * 64;
#pragma unroll
    for (unsigned c = 0; c < 4; ++c) {
      unsigned idx = c * 256 + tid;
      unsigned row = idx >> 3, ch = idx & 7;
      unsigned chs = ch ^ (row & 7);
      unsigned m = tm * 128 + row;
      unsigned t = m >> 5, b = m & 31;
      int e = seq[b * 2048 + t];
      const f16* src = emb16 + ((size_t)e << 10) + k0 + chs * 8;
      gl_lds16(src, (char*)As + c * 4096 + w * 1024);
    }
#pragma unroll
    for (unsigned c = 0; c < 4; ++c) {
      unsigned idx = c * 256 + tid;
      unsigned row = idx >> 3, ch = idx & 7;
      unsigned chs = ch ^ (row & 7);
      unsigned n = tn * 128 + row;
      const f16* src = wih16 + ((size_t)n << 10) + k0 + chs * 8;
      gl_lds16(src, (char*)Bs + c * 4096 + w * 1024);
    }
    __syncthreads();
#pragma unroll
    for (unsigned ks = 0; ks < 2; ++ks) {
      f16x8 af[4], bf[4];
      unsigned kc = ks * 4 + (lane >> 4);
#pragma unroll
      for (unsigned fm = 0; fm < 4; ++fm) {
        unsigned r = wm + fm * 16 + (lane & 15);
        af[fm] = *(const f16x8*)&As[r * 64 + ((kc ^ (r & 7)) << 3)];
      }
#pragma unroll
      for (unsigned fn = 0; fn < 4; ++fn) {
        unsigned r = wn + fn * 16 + (lane & 15);
        bf[fn] = *(const f16x8*)&Bs[r * 64 + ((kc ^ (r & 7)) << 3)];
      }
#pragma unroll
      for (unsigned fm = 0; fm < 4; ++fm)
#pragma unroll
        for (unsigned fn = 0; fn < 4; ++fn)
          acc[fm][fn] = __builtin_amdgcn_mfma_f32_16x16x32_f16(af[fm], bf[fn], acc[fm][fn], 0, 0, 0);
    }
    __syncthreads();
  }
  // epilogue: + bias, fp16 store into gate-interleaved layout R'
#pragma unroll
  for (unsigned fn = 0; fn < 4; ++fn) {
    unsigned n = tn * 128 + wn + fn * 16 + (lane & 15);
    unsigned q = n >> 10, j = n & 1023;
    unsigned Rp = ((j >> 4) << 6) + ((j & 15) << 2) + q;
    float bv = bias[n];
#pragma unroll
    for (unsigned fm = 0; fm < 4; ++fm) {
#pragma unroll
      for (unsigned rg = 0; rg < 4; ++rg) {
        unsigned m = tm * 128 + wm + fm * 16 + (lane >> 4) * 4 + rg;
        xg[(size_t)m * G4_ + Rp] = (f16)(acc[fm][fn][rg] + bv);
      }
    }
  }
}

// ---------------- persistent LSTM recurrence ----------------
// 64 WGs x 512 threads (8 waves = 2 M-tiles x 4 N-tiles). WG wid owns h-dims
// [wid*16, wid*16+16) -> 64 gate-interleaved rows staged once in 128KB LDS.
// Clean sc1 protocol (no wbl2/inv/fences/RMW anywhere in the loop):
//   h transport: relaxed sc1 64-bit loads / 16-bit stores (LLC-coherent).
//   release: __syncthreads (per-wave vmcnt(0) drain => h in LLC) then tid0
//            relaxed-stores flag[wid] = t (own 128B line).
//   acquire: wave0's 64 lanes relaxed-poll the 64 flags, __all(v >= t-1);
//            barrier. No cache maintenance: sc1 ops never hit stale L1/L2.
// xg loads for step t issued at loop top (complete under the poll).

__global__ __launch_bounds__(512) void k_lstm(
    const f16* __restrict__ xg, const f16* __restrict__ wr16,
    f16* __restrict__ h_all, unsigned* __restrict__ flags) {
  __shared__ f16 Wl[64 * 1024];     // 128 KB
  const unsigned tid = threadIdx.x;
  const unsigned w = tid >> 6, lane = tid & 63;
  const unsigned wid = blockIdx.x;          // 0..63
  const unsigned mt = w >> 2, nt = w & 3;

  // stage W_hh slice (64 rows x 1024 f16), source-swizzled, linear LDS dest
  for (unsigned c = 0; c < 16; ++c) {
    unsigned idx = c * 512 + tid;
    unsigned row = idx >> 7, ch = idx & 127;
    unsigned chs = ch ^ (row & 7);
    const f16* src = wr16 + (((size_t)wid * 64 + row) << 10) + chs * 8;
    gl_lds16(src, (char*)Wl + c * 8192 + w * 1024);
  }
  __syncthreads();

  const unsigned rl = lane & 15, hi = lane >> 4;
  const unsigned q = rl & 3;                 // gate id within quad
  const unsigned rWl = nt * 16 + rl;         // local W row 0..63
  const unsigned bB = mt * 16 + hi * 4;      // batch base for the 4 acc regs
  const unsigned d = wid * 16 + nt * 4 + (rl >> 2);
  float c_st[4] = {0.f, 0.f, 0.f, 0.f};

  for (unsigned t = 1; t <= (unsigned)T_; ++t) {
    // x_gates for step t (independent of h -> issues before the poll)
    float xv[4];
    {
      const f16* xp = xg + ((size_t)(t - 1) * B_ + bB) * G4_ + wid * 64 + rWl;
#pragma unroll
      for (int z = 0; z < 4; ++z) xv[z] = (float)xp[(size_t)z * G4_];
    }
    if (t > 1) {
      if (tid < 64) {
        while (true) {
          unsigned v = __hip_atomic_load(&flags[tid * 32], __ATOMIC_RELAXED,
                                         __HIP_MEMORY_SCOPE_AGENT);
          if (__all((int)(v >= t - 1))) break;
        }
      }
      __syncthreads();
    }
    // gates_partial = h_{t-1}[m-tile] @ Whh_slice[n-tile]^T ; A-frags from LLC
    f32x4 acc0 = {0.f, 0.f, 0.f, 0.f};
    f32x4 acc1 = {0.f, 0.f, 0.f, 0.f};
    const f16* hrow = h_all + ((size_t)(t - 1) * B_ + mt * 16 + rl) * H_ + hi * 8;
#pragma unroll
    for (unsigned ks = 0; ks < 32; ks += 2) {
      union { u64 u[2]; f16x8 v; } ua, ub;
      ua.u[0] = llc_ld64(hrow + ks * 32);
      ua.u[1] = llc_ld64(hrow + ks * 32 + 4);
      ub.u[0] = llc_ld64(hrow + ks * 32 + 32);
      ub.u[1] = llc_ld64(hrow + ks * 32 + 36);
      unsigned ck0 = ks * 4 + hi, ck1 = ck0 + 4;
      f16x8 b0 = *(const f16x8*)&Wl[rWl * 1024 + ((ck0 ^ (rWl & 7)) << 3)];
      f16x8 b1 = *(const f16x8*)&Wl[rWl * 1024 + ((ck1 ^ (rWl & 7)) << 3)];
      acc0 = __builtin_amdgcn_mfma_f32_16x16x32_f16(ua.v, b0, acc0, 0, 0, 0);
      acc1 = __builtin_amdgcn_mfma_f32_16x16x32_f16(ub.v, b1, acc1, 0, 0, 0);
    }
    // activations + state update (each quad holds i,f,g,o of one (d, b-set))
    f16* hw = h_all + ((size_t)t * B_ + bB) * H_ + d;
#pragma unroll
    for (int z = 0; z < 4; ++z) {
      float v = acc0[z] + acc1[z] + xv[z];
      float a = (q == 2) ? fast_tanh(v) : fast_sigmoid(v);
      float A1 = __shfl_xor(a, 1, 64);
      float A2 = __shfl_xor(a, 2, 64);
      float A3 = __shfl_xor(a, 3, 64);
      float iact = (q == 0) ? a  : (q == 1) ? A1 : (q == 2) ? A2 : A3;
      float fact = (q == 0) ? A1 : (q == 1) ? a  : (q == 2) ? A3 : A2;
      float gact = (q == 0) ? A2 : (q == 1) ? A3 : (q == 2) ? a  : A1;
      float oact = (q == 0) ? A3 : (q == 1) ? A2 : (q == 2) ? A1 : a;
      float cn = fact * c_st[z] + iact * gact;
      c_st[z] = cn;
      float hv = oact * fast_tanh(cn);
      if (q == 0) {
        f16 hv16 = (f16)hv;
        llc_st16(hw + (size_t)z * H_, __builtin_bit_cast(unsigned short, hv16));
      }
    }
    __syncthreads();   // each wave drains vmcnt(0) before s_barrier => h in LLC
    if (tid == 0) {
      __hip_atomic_store(&flags[wid * 32], t, __ATOMIC_RELAXED,
                         __HIP_MEMORY_SCOPE_AGENT);
    }
  }
}

// ---------------- logits: out[b][t][c] = relu(h[t+1]) . W_score[c] ----------------

__global__ __launch_bounds__(256) void k_logits(
    const f16* __restrict__ h_all, const float* __restrict__ wsc,
    float* __restrict__ out) {
  __shared__ float Ws[2048];
  unsigned tid = threadIdx.x;
  for (unsigned i = tid; i < 512; i += 256) ((float4*)Ws)[i] = ((const float4*)wsc)[i];
  __syncthreads();
  unsigned w = tid >> 6, lane = tid & 63;
  unsigned base = blockIdx.x * 64 + w * 16;
  for (unsigned i = 0; i < 16; ++i) {
    unsigned idx = base + i;                // 0..65535
    unsigned tt = idx >> 5, b = idx & 31;
    const f16* hp = h_all + ((size_t)(idx + 32)) * H_ + lane * 16;
    f16x8 ha = *(const f16x8*)hp;
    f16x8 hb = *(const f16x8*)(hp + 8);
    float s0 = 0.f, s1 = 0.f;
#pragma unroll
    for (int z = 0; z < 8; ++z) {
      float hv = fmaxf((float)ha[z], 0.f);
      s0 += hv * Ws[lane * 16 + z];
      s1 += hv * Ws[1024 + lane * 16 + z];
    }
#pragma unroll
    for (int z = 0; z < 8; ++z) {
      float hv = fmaxf((float)hb[z], 0.f);
      s0 += hv * Ws[lane * 16 + 8 + z];
      s1 += hv * Ws[1024 + lane * 16 + 8 + z];
    }
#pragma unroll
    for (int off = 32; off; off >>= 1) {
      s0 += __shfl_xor(s0, off, 64);
      s1 += __shfl_xor(s1, off, 64);
    }
    if (lane == 0) {
      out[((size_t)b * T_ + tt) * 2 + 0] = s0;
      out[((size_t)b * T_ + tt) * 2 + 1] = s1;
    }
  }
}

// ---------------- launch ----------------

extern "C" void kernel_launch(void* const* d_in, const int* in_sizes, int n_in,
                              void* d_out, int out_size, void* d_ws, size_t ws_size,
                              hipStream_t stream) {
  const int*   seq = (const int*)d_in[0];
  const float* emb = (const float*)d_in[1];
  const float* wih = (const float*)d_in[2];
  const float* whh = (const float*)d_in[3];
  const float* bih = (const float*)d_in[4];
  const float* bhh = (const float*)d_in[5];
  const float* wsc = (const float*)d_in[6];
  float* out = (float*)d_out;
  char* ws = (char*)d_ws;

  const size_t NEED = 790882304ull;
  if (ws_size < NEED) return;  // workspace too small: output stays zero (detectable)

  f16*      emb16 = (f16*)(ws);
  f16*      wih16 = (f16*)(ws + 102926336ull);
  f16*      wr16  = (f16*)(ws + 111314944ull);
  float*    bias  = (float*)(ws + 119703552ull);
  f16*      xg    = (f16*)(ws + 119719936ull);
  f16*      h_all = (f16*)(ws + 656590848ull);
  unsigned* flags = (unsigned*)(ws + 790874112ull);

  hipMemsetAsync(h_all, 0, (size_t)B_ * H_ * 2, stream);      // h_0 = 0
  hipMemsetAsync(flags, 0, 64 * 32 * 4, stream);              // step flags

  k_cvt_f16<<<50257, 256, 0, stream>>>(emb, emb16, 12865792L);
  k_cvt_f16<<<4096, 256, 0, stream>>>(wih, wih16, 1048576L);
  k_whh_reorder<<<2048, 256, 0, stream>>>(whh, wr16);
  k_bias<<<16, 256, 0, stream>>>(bih, bhh, bias);

  k_gemm_xg<<<16384, 256, 0, stream>>>(seq, emb16, wih16, bias, xg);
  k_lstm<<<64, 512, 0, stream>>>(xg, wr16, h_all, flags);
  k_logits<<<1024, 256, 0, stream>>>(h_all, wsc, out);
}

// Round 8
// 20366.983 us; speedup vs baseline: 3.5715x; 1.6628x over previous
//
#include <hip/hip_runtime.h>
#include <hip/hip_bf16.h>

// LSTM classifier: emb gather -> input GEMM (fp16 MFMA) -> persistent
// recurrence with DATA-CARRIED sync (poison-tagged h words; no flags, no
// fences, no barriers across WGs) -> logits.
//
// Workspace layout (bytes):
//   emb16   @ 0          : 50257*1024*2 = 102,926,336
//   wih16   @ 102926336  : 4096*1024*2  =   8,388,608
//   wr16    @ 111314944  : 4096*1024*2  =   8,388,608   (W_hh reordered, fp16)
//   bias    @ 119703552  : 4096*4       =      16,384   (b_ih + b_hh, f32)
//   xg      @ 119719936  : 65536*4096*2 = 536,870,912   (x_gates fp16, [t][b][R'])
//   h_all   @ 656590848  : 2049*32*1024*2 = 134,283,264 (h; t>=1 poisoned 0xFFFF per launch)
//   total: 790,874,112

typedef _Float16 f16;
typedef _Float16 f16x8 __attribute__((ext_vector_type(8)));
typedef _Float16 f16x4 __attribute__((ext_vector_type(4)));
typedef float    f32x4 __attribute__((ext_vector_type(4)));
typedef unsigned long long u64;

#define B_    32
#define T_    2048
#define H_    1024
#define G4_   4096

__device__ __forceinline__ void gl_lds16(const void* g, void* l) {
  __builtin_amdgcn_global_load_lds(
      (const __attribute__((address_space(1))) void*)g,
      (__attribute__((address_space(3))) void*)l, 16, 0, 0);
}

// agent-scope (LLC) 8B store — write-through past the non-coherent XCD L2s
__device__ __forceinline__ void llc_st64(void* p, u64 v) {
  __hip_atomic_store((u64*)p, v, __ATOMIC_RELAXED, __HIP_MEMORY_SCOPE_AGENT);
}

// fast activations: v_exp_f32 + v_rcp_f32 (no libm branches on critical path)
__device__ __forceinline__ float fast_sigmoid(float v) {
  return __builtin_amdgcn_rcpf(1.f + __expf(-v));
}
__device__ __forceinline__ float fast_tanh(float v) {
  return 1.f - 2.f * __builtin_amdgcn_rcpf(1.f + __expf(2.f * v));
}

// ---------------- conversions ----------------

__global__ void k_cvt_f16(const float* __restrict__ in, f16* __restrict__ out, long n4) {
  long i = (long)blockIdx.x * blockDim.x + threadIdx.x;
  if (i >= n4) return;
  float4 v = ((const float4*)in)[i];
  f16x4 o; o[0] = (f16)v.x; o[1] = (f16)v.y; o[2] = (f16)v.z; o[3] = (f16)v.w;
  *(f16x4*)(out + i * 4) = o;
}

// W_hh row (q*1024 + j) -> wr16 row R' = (j>>4)*64 + (j&15)*4 + q; fp16.
// => WG wid owns contiguous rows [wid*64, wid*64+64) = h-dims [wid*16, +16).
__global__ void k_whh_reorder(const float* __restrict__ whh, f16* __restrict__ wr) {
  unsigned i = blockIdx.x * blockDim.x + threadIdx.x;   // one thread per 8 elems
  unsigned e0 = i * 8;
  unsigned R = e0 >> 10, k = e0 & 1023;
  unsigned q = R >> 10, j = R & 1023;
  unsigned outR = ((j >> 4) << 6) + ((j & 15) << 2) + q;
  float4 v0 = ((const float4*)whh)[e0 / 4];
  float4 v1 = ((const float4*)whh)[e0 / 4 + 1];
  f16x8 o;
  o[0] = (f16)v0.x; o[1] = (f16)v0.y; o[2] = (f16)v0.z; o[3] = (f16)v0.w;
  o[4] = (f16)v1.x; o[5] = (f16)v1.y; o[6] = (f16)v1.z; o[7] = (f16)v1.w;
  *(f16x8*)&wr[((size_t)outR << 10) + k] = o;
}

__global__ void k_bias(const float* __restrict__ bi, const float* __restrict__ bh,
                       float* __restrict__ bo) {
  unsigned i = blockIdx.x * blockDim.x + threadIdx.x;
  if (i < G4_) bo[i] = bi[i] + bh[i];
}

// ---------------- input GEMM: xg[m][R'(n)] = emb[seq] @ W_ih^T + bias ----------------
// m = t*32 + b (so xg layout is [t][b][R']); 128x128 tile, BK=64, 4 waves.

__global__ __launch_bounds__(256) void k_gemm_xg(
    const int* __restrict__ seq, const f16* __restrict__ emb16,
    const f16* __restrict__ wih16, const float* __restrict__ bias,
    f16* __restrict__ xg) {
  __shared__ f16 As[128 * 64];
  __shared__ f16 Bs[128 * 64];
  const unsigned tid = threadIdx.x;
  const unsigned w = tid >> 6, lane = tid & 63;
  const unsigned bid = blockIdx.x;
  const unsigned tn = bid & 31, tm = bid >> 5;
  const unsigned wm = (w >> 1) * 64, wn = (w & 1) * 64;

  f32x4 zero = {0.f, 0.f, 0.f, 0.f};
  f32x4 acc[4][4];
#pragma unroll
  for (int i = 0; i < 4; ++i)
#pragma unroll
    for (int j = 0; j < 4; ++j) acc[i][j] = zero;

  for (unsigned kk = 0; kk < 16; ++kk) {
    const unsigned k0 = kk * 64;
#pragma unroll
    for (unsigned c = 0; c < 4; ++c) {
      unsigned idx = c * 256 + tid;
      unsigned row = idx >> 3, ch = idx & 7;
      unsigned chs = ch ^ (row & 7);
      unsigned m = tm * 128 + row;
      unsigned t = m >> 5, b = m & 31;
      int e = seq[b * 2048 + t];
      const f16* src = emb16 + ((size_t)e << 10) + k0 + chs * 8;
      gl_lds16(src, (char*)As + c * 4096 + w * 1024);
    }
#pragma unroll
    for (unsigned c = 0; c < 4; ++c) {
      unsigned idx = c * 256 + tid;
      unsigned row = idx >> 3, ch = idx & 7;
      unsigned chs = ch ^ (row & 7);
      unsigned n = tn * 128 + row;
      const f16* src = wih16 + ((size_t)n << 10) + k0 + chs * 8;
      gl_lds16(src, (char*)Bs + c * 4096 + w * 1024);
    }
    __syncthreads();
#pragma unroll
    for (unsigned ks = 0; ks < 2; ++ks) {
      f16x8 af[4], bf[4];
      unsigned kc = ks * 4 + (lane >> 4);
#pragma unroll
      for (unsigned fm = 0; fm < 4; ++fm) {
        unsigned r = wm + fm * 16 + (lane & 15);
        af[fm] = *(const f16x8*)&As[r * 64 + ((kc ^ (r & 7)) << 3)];
      }
#pragma unroll
      for (unsigned fn = 0; fn < 4; ++fn) {
        unsigned r = wn + fn * 16 + (lane & 15);
        bf[fn] = *(const f16x8*)&Bs[r * 64 + ((kc ^ (r & 7)) << 3)];
      }
#pragma unroll
      for (unsigned fm = 0; fm < 4; ++fm)
#pragma unroll
        for (unsigned fn = 0; fn < 4; ++fn)
          acc[fm][fn] = __builtin_amdgcn_mfma_f32_16x16x32_f16(af[fm], bf[fn], acc[fm][fn], 0, 0, 0);
    }
    __syncthreads();
  }
  // epilogue: + bias, fp16 store into gate-interleaved layout R'
#pragma unroll
  for (unsigned fn = 0; fn < 4; ++fn) {
    unsigned n = tn * 128 + wn + fn * 16 + (lane & 15);
    unsigned q = n >> 10, j = n & 1023;
    unsigned Rp = ((j >> 4) << 6) + ((j & 15) << 2) + q;
    float bv = bias[n];
#pragma unroll
    for (unsigned fm = 0; fm < 4; ++fm) {
#pragma unroll
      for (unsigned rg = 0; rg < 4; ++rg) {
        unsigned m = tm * 128 + wm + fm * 16 + (lane >> 4) * 4 + rg;
        xg[(size_t)m * G4_ + Rp] = (f16)(acc[fm][fn][rg] + bv);
      }
    }
  }
}

// ---------------- persistent LSTM recurrence, data-carried sync ----------------
// 64 WGs x 512 threads (8 waves = 2 M-tiles x 4 N-tiles). WG wid owns h-dims
// [wid*16, wid*16+16). W_hh slice: k<512 in 64KB LDS, k>=512 in 64 VGPRs/lane
// (asm-pinned, R6-validated). h_all[t>=1] poisoned 0xFFFF per launch; h values
// are in (-1,1) so 0xFFFF (f16 -NaN) never occurs naturally.
// Per step: each thread spin-loads its own 128B slice of h_{t-1} (8x16B
// sc0 sc1 LLC loads) until no 8B granule is all-poison -> ds_write into 64KB
// swizzled LDS h-tile -> barrier -> MFMA (A and B from LDS/regs) -> barrier ->
// activations -> pack 4 dims/8B via shuffles -> 16 sc1 stores/wave. The spin
// IS the sync: no flags, no fences, no release waits, waves never block on
// anything but the exact data they need.

__global__ __launch_bounds__(512) void k_lstm(
    const f16* __restrict__ xg, const f16* __restrict__ wr16,
    f16* __restrict__ h_all) {
  __shared__ f16 Wl[64 * 512];    // 64 KB: W_hh slice, k < 512
  __shared__ f16 Hl[32 * 1024];   // 64 KB: h_{t-1} staging tile
  const unsigned tid = threadIdx.x;
  const unsigned w = tid >> 6, lane = tid & 63;
  const unsigned wid = blockIdx.x;          // 0..63
  const unsigned mt = w >> 2, nt = w & 3;

  // stage W k<512 (64 rows x 64 16B-chunks), source-swizzled, linear LDS dest
  for (unsigned c = 0; c < 8; ++c) {
    unsigned idx = c * 512 + tid;
    unsigned row = idx >> 6, ch = idx & 63;
    unsigned chs = ch ^ (row & 7);
    const f16* src = wr16 + (((size_t)wid * 64 + row) << 10) + chs * 8;
    gl_lds16(src, (char*)Wl + c * 8192 + w * 1024);
  }

  const unsigned rl = lane & 15, hi = lane >> 4;
  const unsigned q = rl & 3;                 // gate id within quad
  const unsigned rWl = nt * 16 + rl;         // local W row 0..63
  const unsigned bB = mt * 16 + hi * 4;      // batch base of this lane's 4 accs
  const unsigned d0 = wid * 16 + nt * 4;     // first h-dim of this wave's quad row
  const unsigned arow = mt * 16 + rl;        // A-tile row (batch) in Hl

  // B-frags k in [512,1024): pinned in VGPRs via asm (cannot sink/remat - R3 lesson)
  f16x8 breg[16];
  {
    const f16* wp = wr16 + (((size_t)wid * 64 + rWl) << 10) + 512 + hi * 8;
#pragma unroll
    for (int j = 0; j < 16; ++j) {
      asm volatile("global_load_dwordx4 %0, %1, off\n\ts_waitcnt vmcnt(0)"
                   : "=v"(breg[j]) : "v"(wp + j * 32) : "memory");
    }
  }
  __syncthreads();   // Wl staged + breg loaded

  // staging assignment: batch row = tid>>4, f16 col base = (tid&15)*64 (128B)
  const unsigned srow = tid >> 4;
  const unsigned scol = (tid & 15) << 6;
  float c_st[4] = {0.f, 0.f, 0.f, 0.f};

  for (unsigned t = 1; t <= (unsigned)T_; ++t) {
    // x_gates for step t (plain loads, L2-cached; complete under the spin)
    float xv[4];
    {
      const f16* xp = xg + ((size_t)(t - 1) * B_ + bB) * G4_ + wid * 64 + rWl;
#pragma unroll
      for (int z = 0; z < 4; ++z) xv[z] = (float)xp[(size_t)z * G4_];
    }
    // ---- data-driven staging: spin on own 128B slice of h_{t-1} ----
    const f16* gp = h_all + ((size_t)(t - 1) * B_ + srow) * H_ + scol;
    f16x8 st[8];
    while (true) {
#pragma unroll
      for (int j = 0; j < 8; ++j)
        asm volatile("global_load_dwordx4 %0, %1, off sc0 sc1"
                     : "=v"(st[j]) : "v"(gp + j * 8));
      asm volatile("s_waitcnt vmcnt(0)" ::: "memory");
      __builtin_amdgcn_sched_barrier(0);   // rule #18: pin the check after the wait
      bool ok = true;
#pragma unroll
      for (int j = 0; j < 8; ++j) {
        union { f16x8 v; u64 u[2]; } uu; uu.v = st[j];
        ok = ok && (uu.u[0] != ~0ull) && (uu.u[1] != ~0ull);
      }
      if (ok) break;
      __builtin_amdgcn_s_sleep(1);
    }
#pragma unroll
    for (int j = 0; j < 8; ++j) {
      unsigned cc = (tid & 15) * 8 + j;    // 16B chunk index within row
      *(f16x8*)&Hl[srow * 1024 + ((cc ^ (srow & 7)) << 3)] = st[j];
    }
    __syncthreads();   // h-tile ready for all waves

    // ---- gates = h_{t-1}[m-tile] @ Whh_slice[n-tile]^T (A from Hl) ----
    f32x4 acc0 = {0.f, 0.f, 0.f, 0.f};
    f32x4 acc1 = {0.f, 0.f, 0.f, 0.f};
#pragma unroll
    for (unsigned ks = 0; ks < 16; ks += 2) {
      unsigned c0 = ks * 4 + hi, c1 = c0 + 4;
      f16x8 a0 = *(const f16x8*)&Hl[arow * 1024 + ((c0 ^ (arow & 7)) << 3)];
      f16x8 a1 = *(const f16x8*)&Hl[arow * 1024 + ((c1 ^ (arow & 7)) << 3)];
      f16x8 b0 = *(const f16x8*)&Wl[rWl * 512 + ((c0 ^ (rWl & 7)) << 3)];
      f16x8 b1 = *(const f16x8*)&Wl[rWl * 512 + ((c1 ^ (rWl & 7)) << 3)];
      acc0 = __builtin_amdgcn_mfma_f32_16x16x32_f16(a0, b0, acc0, 0, 0, 0);
      acc1 = __builtin_amdgcn_mfma_f32_16x16x32_f16(a1, b1, acc1, 0, 0, 0);
    }
#pragma unroll
    for (unsigned ks = 16; ks < 32; ks += 2) {
      unsigned c0 = ks * 4 + hi, c1 = c0 + 4;
      f16x8 a0 = *(const f16x8*)&Hl[arow * 1024 + ((c0 ^ (arow & 7)) << 3)];
      f16x8 a1 = *(const f16x8*)&Hl[arow * 1024 + ((c1 ^ (arow & 7)) << 3)];
      acc0 = __builtin_amdgcn_mfma_f32_16x16x32_f16(a0, breg[ks - 16], acc0, 0, 0, 0);
      acc1 = __builtin_amdgcn_mfma_f32_16x16x32_f16(a1, breg[ks - 15], acc1, 0, 0, 0);
    }
    __syncthreads();   // all Hl reads done -> next iteration may overwrite

    // ---- activations + state update (quad holds i,f,g,o of one (d, b-set)) ----
    float hv[4];
#pragma unroll
    for (int z = 0; z < 4; ++z) {
      float v = acc0[z] + acc1[z] + xv[z];
      float a = (q == 2) ? fast_tanh(v) : fast_sigmoid(v);
      float A1 = __shfl_xor(a, 1, 64);
      float A2 = __shfl_xor(a, 2, 64);
      float A3 = __shfl_xor(a, 3, 64);
      float iact = (q == 0) ? a  : (q == 1) ? A1 : (q == 2) ? A2 : A3;
      float fact = (q == 0) ? A1 : (q == 1) ? a  : (q == 2) ? A3 : A2;
      float gact = (q == 0) ? A2 : (q == 1) ? A3 : (q == 2) ? a  : A1;
      float oact = (q == 0) ? A3 : (q == 1) ? A2 : (q == 2) ? A1 : a;
      float cn = fact * c_st[z] + iact * gact;
      c_st[z] = cn;
      hv[z] = oact * fast_tanh(cn);
    }
    // ---- pack h(d0..d0+3) per batch into 8B, store via sc1 (16/wave) ----
    // g[j][z] = hv[z] pulled from quad j (holds dim d0+j); all lanes shuffle.
    unsigned sb = lane & 48;   // hi*16
    float g[4][4];
#pragma unroll
    for (int j = 0; j < 4; ++j) {
      g[j][0] = __shfl(hv[0], (int)(sb | (j << 2)), 64);
      g[j][1] = __shfl(hv[1], (int)(sb | (j << 2)), 64);
      g[j][2] = __shfl(hv[2], (int)(sb | (j << 2)), 64);
      g[j][3] = __shfl(hv[3], (int)(sb | (j << 2)), 64);
    }
    if ((rl & 3) == 0) {
      unsigned zb = rl >> 2;   // this lane stores batch bB+zb
      union { f16 h4[4]; u64 u; } pk;
#pragma unroll
      for (int j = 0; j < 4; ++j) {
        float tv = (zb == 0) ? g[j][0] : (zb == 1) ? g[j][1]
                 : (zb == 2) ? g[j][2] : g[j][3];
        pk.h4[j] = (f16)tv;
      }
      f16* hw = h_all + ((size_t)t * B_ + bB + zb) * H_ + d0;
      llc_st64(hw, pk.u);
    }
    // no release: stores drain under the next step's spin (vmcnt(0) there)
  }
}

// ---------------- logits: out[b][t][c] = relu(h[t+1]) . W_score[c] ----------------

__global__ __launch_bounds__(256) void k_logits(
    const f16* __restrict__ h_all, const float* __restrict__ wsc,
    float* __restrict__ out) {
  __shared__ float Ws[2048];
  unsigned tid = threadIdx.x;
  for (unsigned i = tid; i < 512; i += 256) ((float4*)Ws)[i] = ((const float4*)wsc)[i];
  __syncthreads();
  unsigned w = tid >> 6, lane = tid & 63;
  unsigned base = blockIdx.x * 64 + w * 16;
  for (unsigned i = 0; i < 16; ++i) {
    unsigned idx = base + i;                // 0..65535
    unsigned tt = idx >> 5, b = idx & 31;
    const f16* hp = h_all + ((size_t)(idx + 32)) * H_ + lane * 16;
    f16x8 ha = *(const f16x8*)hp;
    f16x8 hb = *(const f16x8*)(hp + 8);
    float s0 = 0.f, s1 = 0.f;
#pragma unroll
    for (int z = 0; z < 8; ++z) {
      float hv = fmaxf((float)ha[z], 0.f);
      s0 += hv * Ws[lane * 16 + z];
      s1 += hv * Ws[1024 + lane * 16 + z];
    }
#pragma unroll
    for (int z = 0; z < 8; ++z) {
      float hv = fmaxf((float)hb[z], 0.f);
      s0 += hv * Ws[lane * 16 + 8 + z];
      s1 += hv * Ws[1024 + lane * 16 + 8 + z];
    }
#pragma unroll
    for (int off = 32; off; off >>= 1) {
      s0 += __shfl_xor(s0, off, 64);
      s1 += __shfl_xor(s1, off, 64);
    }
    if (lane == 0) {
      out[((size_t)b * T_ + tt) * 2 + 0] = s0;
      out[((size_t)b * T_ + tt) * 2 + 1] = s1;
    }
  }
}

// ---------------- launch ----------------

extern "C" void kernel_launch(void* const* d_in, const int* in_sizes, int n_in,
                              void* d_out, int out_size, void* d_ws, size_t ws_size,
                              hipStream_t stream) {
  const int*   seq = (const int*)d_in[0];
  const float* emb = (const float*)d_in[1];
  const float* wih = (const float*)d_in[2];
  const float* whh = (const float*)d_in[3];
  const float* bih = (const float*)d_in[4];
  const float* bhh = (const float*)d_in[5];
  const float* wsc = (const float*)d_in[6];
  float* out = (float*)d_out;
  char* ws = (char*)d_ws;

  const size_t NEED = 790874112ull;
  if (ws_size < NEED) return;  // workspace too small: output stays zero (detectable)

  f16*   emb16 = (f16*)(ws);
  f16*   wih16 = (f16*)(ws + 102926336ull);
  f16*   wr16  = (f16*)(ws + 111314944ull);
  float* bias  = (float*)(ws + 119703552ull);
  f16*   xg    = (f16*)(ws + 119719936ull);
  f16*   h_all = (f16*)(ws + 656590848ull);

  hipMemsetAsync(h_all, 0, (size_t)B_ * H_ * 2, stream);                // h_0 = 0
  hipMemsetAsync((char*)h_all + (size_t)B_ * H_ * 2, 0xFF,
                 (size_t)T_ * B_ * H_ * 2, stream);                     // poison h_1..h_T

  k_cvt_f16<<<50257, 256, 0, stream>>>(emb, emb16, 12865792L);
  k_cvt_f16<<<4096, 256, 0, stream>>>(wih, wih16, 1048576L);
  k_whh_reorder<<<2048, 256, 0, stream>>>(whh, wr16);
  k_bias<<<16, 256, 0, stream>>>(bih, bhh, bias);

  k_gemm_xg<<<16384, 256, 0, stream>>>(seq, emb16, wih16, bias, xg);
  k_lstm<<<64, 512, 0, stream>>>(xg, wr16, h_all);
  k_logits<<<1024, 256, 0, stream>>>(h_all, wsc, out);
}